// Round 1
// baseline (623.743 us; speedup 1.0000x reference)
//
#include <hip/hip_runtime.h>
#include <hip/hip_bf16.h>
#include <math.h>

// ---------------------------------------------------------------------------
// GCN forward: out = log_softmax( A@( relu(A@(x@W1)+b1) @ W2 ) + b2 )
// A is COO with SORTED rows -> CSR via binary-searched row_ptr.
// Round 0: fp32 everywhere, correctness-first baseline.
// ---------------------------------------------------------------------------

#define GCN_NFEAT 256
#define GCN_NHID  128
#define GCN_NCLASS 40

// ---- row_ptr[r] = lower_bound(adj_row, r), r in [0, N] ---------------------
__global__ __launch_bounds__(256) void k_row_ptr(
    const int* __restrict__ row, int* __restrict__ row_ptr, int n_rows, int n_edges)
{
    int r = blockIdx.x * blockDim.x + threadIdx.x;
    if (r > n_rows) return;
    int lo = 0, hi = n_edges;
    while (lo < hi) {
        int mid = (lo + hi) >> 1;
        if (row[mid] < r) lo = mid + 1; else hi = mid;
    }
    row_ptr[r] = lo;
}

// ---- GEMM1: support1[N,128] = x[N,256] @ W1[256,128] -----------------------
// 128-row x 128-col tile per 256-thread block, K-chunks of 16, 8x8 acc/thread.
__global__ __launch_bounds__(256) void k_gemm1(
    const float* __restrict__ x, const float* __restrict__ w1,
    float* __restrict__ out, int nrows)
{
    __shared__ float xs[16][128 + 4];   // xs[k][row]  (transposed for b128 reads)
    __shared__ float ws[16][128 + 4];   // ws[k][col]

    const int tid = threadIdx.x;
    const int r0  = blockIdx.x * 128;
    const int tx  = tid & 15;    // col group -> cols tx*8 .. tx*8+7
    const int ty  = tid >> 4;    // row group -> rows ty*8 .. ty*8+7

    float acc[8][8];
#pragma unroll
    for (int i = 0; i < 8; i++)
#pragma unroll
        for (int j = 0; j < 8; j++) acc[i][j] = 0.f;

    for (int k0 = 0; k0 < GCN_NFEAT; k0 += 16) {
        // stage x tile: thread -> (row = tid/2, 8 k's)
        {
            const int row = tid >> 1;
            const int kb  = (tid & 1) * 8;
            const int gr  = r0 + row;
            float4 v0 = make_float4(0.f, 0.f, 0.f, 0.f), v1 = v0;
            if (gr < nrows) {
                const float* p = x + (size_t)gr * GCN_NFEAT + k0 + kb;
                v0 = *(const float4*)p;
                v1 = *(const float4*)(p + 4);
            }
            xs[kb + 0][row] = v0.x; xs[kb + 1][row] = v0.y;
            xs[kb + 2][row] = v0.z; xs[kb + 3][row] = v0.w;
            xs[kb + 4][row] = v1.x; xs[kb + 5][row] = v1.y;
            xs[kb + 6][row] = v1.z; xs[kb + 7][row] = v1.w;
        }
        // stage W1 tile: thread -> (k = tid/16, 8 cols)
        {
            const int k = tid >> 4;
            const int c = (tid & 15) * 8;
            const float* p = w1 + (size_t)(k0 + k) * GCN_NHID + c;
            *(float4*)&ws[k][c]     = *(const float4*)p;
            *(float4*)&ws[k][c + 4] = *(const float4*)(p + 4);
        }
        __syncthreads();

#pragma unroll
        for (int kk = 0; kk < 16; kk++) {
            float a[8], b[8];
            *(float4*)&a[0] = *(const float4*)&xs[kk][ty * 8];
            *(float4*)&a[4] = *(const float4*)&xs[kk][ty * 8 + 4];
            *(float4*)&b[0] = *(const float4*)&ws[kk][tx * 8];
            *(float4*)&b[4] = *(const float4*)&ws[kk][tx * 8 + 4];
#pragma unroll
            for (int i = 0; i < 8; i++)
#pragma unroll
                for (int j = 0; j < 8; j++)
                    acc[i][j] = fmaf(a[i], b[j], acc[i][j]);
        }
        __syncthreads();
    }

#pragma unroll
    for (int i = 0; i < 8; i++) {
        const int gr = r0 + ty * 8 + i;
        if (gr < nrows) {
            float* p = out + (size_t)gr * GCN_NHID + tx * 8;
            *(float4*)p       = make_float4(acc[i][0], acc[i][1], acc[i][2], acc[i][3]);
            *(float4*)(p + 4) = make_float4(acc[i][4], acc[i][5], acc[i][6], acc[i][7]);
        }
    }
}

// ---- spmm1: h[r,:] = relu( sum_e val[e]*support1[col[e],:] + b1 ) ----------
// one wave (64 lanes) per row; lane owns 2 of the 128 columns (float2).
__global__ __launch_bounds__(256) void k_spmm1(
    const int* __restrict__ row_ptr, const int* __restrict__ col,
    const float* __restrict__ val, const float* __restrict__ sup,
    const float* __restrict__ b1, float* __restrict__ h, int nrows)
{
    const int wid  = (blockIdx.x * blockDim.x + threadIdx.x) >> 6;
    const int lane = threadIdx.x & 63;
    if (wid >= nrows) return;
    const int r  = wid;
    const int e0 = row_ptr[r];
    const int e1 = row_ptr[r + 1];

    const float* supb = sup + lane * 2;
    float2 acc = make_float2(0.f, 0.f);

    int e = e0;
    for (; e + 3 < e1; e += 4) {
        const int c0 = col[e], c1 = col[e + 1], c2 = col[e + 2], c3 = col[e + 3];
        const float v0 = val[e], v1 = val[e + 1], v2 = val[e + 2], v3 = val[e + 3];
        float2 s0 = *(const float2*)(supb + (size_t)c0 * GCN_NHID);
        float2 s1 = *(const float2*)(supb + (size_t)c1 * GCN_NHID);
        float2 s2 = *(const float2*)(supb + (size_t)c2 * GCN_NHID);
        float2 s3 = *(const float2*)(supb + (size_t)c3 * GCN_NHID);
        acc.x = fmaf(v0, s0.x, acc.x); acc.y = fmaf(v0, s0.y, acc.y);
        acc.x = fmaf(v1, s1.x, acc.x); acc.y = fmaf(v1, s1.y, acc.y);
        acc.x = fmaf(v2, s2.x, acc.x); acc.y = fmaf(v2, s2.y, acc.y);
        acc.x = fmaf(v3, s3.x, acc.x); acc.y = fmaf(v3, s3.y, acc.y);
    }
    for (; e < e1; e++) {
        const int c = col[e];
        const float v = val[e];
        float2 s = *(const float2*)(supb + (size_t)c * GCN_NHID);
        acc.x = fmaf(v, s.x, acc.x); acc.y = fmaf(v, s.y, acc.y);
    }

    const float2 bb = *(const float2*)(b1 + lane * 2);
    float2 o;
    o.x = fmaxf(acc.x + bb.x, 0.f);
    o.y = fmaxf(acc.y + bb.y, 0.f);
    *(float2*)(h + (size_t)r * GCN_NHID + lane * 2) = o;
}

// ---- GEMM2: support2[N,40] = h[N,128] @ W2[128,40] -------------------------
// 128-row tile per 256-thread block; W2 fully in LDS; 4x5 acc/thread.
__global__ __launch_bounds__(256) void k_gemm2(
    const float* __restrict__ h, const float* __restrict__ w2,
    float* __restrict__ out, int nrows)
{
    __shared__ float hs[32][128 + 4];           // hs[k][row]
    __shared__ float ws[GCN_NHID][GCN_NCLASS];  // full W2: 20 KB

    const int tid = threadIdx.x;
    for (int i = tid; i < GCN_NHID * GCN_NCLASS; i += 256)
        ((float*)ws)[i] = w2[i];

    const int r0 = blockIdx.x * 128;
    const int tx = tid & 7;    // cols tx*5 .. tx*5+4
    const int ty = tid >> 3;   // rows ty*4 .. ty*4+3

    float acc[4][5];
#pragma unroll
    for (int i = 0; i < 4; i++)
#pragma unroll
        for (int j = 0; j < 5; j++) acc[i][j] = 0.f;

    for (int k0 = 0; k0 < GCN_NHID; k0 += 32) {
        // stage h tile: thread -> (row = tid/2, 16 k's)
        {
            const int row = tid >> 1;
            const int kb  = (tid & 1) * 16;
            const int gr  = r0 + row;
            float4 q0 = make_float4(0.f,0.f,0.f,0.f), q1 = q0, q2 = q0, q3 = q0;
            if (gr < nrows) {
                const float* p = h + (size_t)gr * GCN_NHID + k0 + kb;
                q0 = *(const float4*)p;      q1 = *(const float4*)(p + 4);
                q2 = *(const float4*)(p + 8); q3 = *(const float4*)(p + 12);
            }
            hs[kb + 0][row] = q0.x;  hs[kb + 1][row] = q0.y;
            hs[kb + 2][row] = q0.z;  hs[kb + 3][row] = q0.w;
            hs[kb + 4][row] = q1.x;  hs[kb + 5][row] = q1.y;
            hs[kb + 6][row] = q1.z;  hs[kb + 7][row] = q1.w;
            hs[kb + 8][row] = q2.x;  hs[kb + 9][row] = q2.y;
            hs[kb +10][row] = q2.z;  hs[kb +11][row] = q2.w;
            hs[kb +12][row] = q3.x;  hs[kb +13][row] = q3.y;
            hs[kb +14][row] = q3.z;  hs[kb +15][row] = q3.w;
        }
        __syncthreads();

#pragma unroll
        for (int kk = 0; kk < 32; kk++) {
            float a[4];
            *(float4*)&a[0] = *(const float4*)&hs[kk][ty * 4];
            float b[5];
#pragma unroll
            for (int j = 0; j < 5; j++) b[j] = ws[k0 + kk][tx * 5 + j];
#pragma unroll
            for (int i = 0; i < 4; i++)
#pragma unroll
                for (int j = 0; j < 5; j++)
                    acc[i][j] = fmaf(a[i], b[j], acc[i][j]);
        }
        __syncthreads();
    }

#pragma unroll
    for (int i = 0; i < 4; i++) {
        const int gr = r0 + ty * 4 + i;
        if (gr < nrows) {
            float* p = out + (size_t)gr * GCN_NCLASS + tx * 5;
#pragma unroll
            for (int j = 0; j < 5; j++) p[j] = acc[i][j];
        }
    }
}

// ---- spmm2 + bias + log_softmax -> out[N,40] -------------------------------
// one wave per row; lanes 0..39 active for gather; shuffle-reduce softmax.
__global__ __launch_bounds__(256) void k_spmm2_lsm(
    const int* __restrict__ row_ptr, const int* __restrict__ col,
    const float* __restrict__ val, const float* __restrict__ sup2,
    const float* __restrict__ b2, float* __restrict__ out, int nrows)
{
    const int wid  = (blockIdx.x * blockDim.x + threadIdx.x) >> 6;
    const int lane = threadIdx.x & 63;
    if (wid >= nrows) return;
    const int r  = wid;
    const int e0 = row_ptr[r];
    const int e1 = row_ptr[r + 1];
    const bool active = lane < GCN_NCLASS;

    float acc = 0.f;
    int e = e0;
    for (; e + 3 < e1; e += 4) {
        const int c0 = col[e], c1 = col[e + 1], c2 = col[e + 2], c3 = col[e + 3];
        const float v0 = val[e], v1 = val[e + 1], v2 = val[e + 2], v3 = val[e + 3];
        if (active) {
            const float s0 = sup2[(size_t)c0 * GCN_NCLASS + lane];
            const float s1 = sup2[(size_t)c1 * GCN_NCLASS + lane];
            const float s2 = sup2[(size_t)c2 * GCN_NCLASS + lane];
            const float s3 = sup2[(size_t)c3 * GCN_NCLASS + lane];
            acc = fmaf(v0, s0, acc);
            acc = fmaf(v1, s1, acc);
            acc = fmaf(v2, s2, acc);
            acc = fmaf(v3, s3, acc);
        }
    }
    for (; e < e1; e++) {
        const int c = col[e];
        const float v = val[e];
        if (active) acc = fmaf(v, sup2[(size_t)c * GCN_NCLASS + lane], acc);
    }

    const float logit = active ? (acc + b2[lane]) : -INFINITY;

    float m = logit;
#pragma unroll
    for (int off = 32; off >= 1; off >>= 1)
        m = fmaxf(m, __shfl_xor(m, off, 64));

    float ex = active ? __expf(logit - m) : 0.f;
    float s = ex;
#pragma unroll
    for (int off = 32; off >= 1; off >>= 1)
        s += __shfl_xor(s, off, 64);

    if (active)
        out[(size_t)r * GCN_NCLASS + lane] = logit - m - __logf(s);
}

// ---------------------------------------------------------------------------
extern "C" void kernel_launch(void* const* d_in, const int* in_sizes, int n_in,
                              void* d_out, int out_size, void* d_ws, size_t ws_size,
                              hipStream_t stream)
{
    const float* x       = (const float*)d_in[0];
    const int*   adj_row = (const int*)  d_in[1];
    const int*   adj_col = (const int*)  d_in[2];
    const float* adj_val = (const float*)d_in[3];
    // d_in[4] = i (unused)
    const float* W1 = (const float*)d_in[5];
    const float* b1 = (const float*)d_in[6];
    const float* W2 = (const float*)d_in[7];
    const float* b2 = (const float*)d_in[8];
    float* out = (float*)d_out;

    const int N = in_sizes[0] / GCN_NFEAT;   // 100000
    const int E = in_sizes[1];               // 3200000

    // workspace layout
    char* ws = (char*)d_ws;
    int*   row_ptr = (int*)ws;
    size_t off = (((size_t)(N + 1) * sizeof(int)) + 1023) & ~(size_t)1023;
    float* sup1 = (float*)(ws + off);                 // N*128 fp32
    float* h    = sup1 + (size_t)N * GCN_NHID;        // N*128 fp32
    float* sup2 = sup1;                               // reuse sup1 region (N*40)

    k_row_ptr<<<(N + 1 + 255) / 256, 256, 0, stream>>>(adj_row, row_ptr, N, E);
    k_gemm1<<<(N + 127) / 128, 256, 0, stream>>>(x, W1, sup1, N);
    k_spmm1<<<(N + 3) / 4, 256, 0, stream>>>(row_ptr, adj_col, adj_val, sup1, b1, h, N);
    k_gemm2<<<(N + 127) / 128, 256, 0, stream>>>(h, W2, sup2, N);
    k_spmm2_lsm<<<(N + 3) / 4, 256, 0, stream>>>(row_ptr, adj_col, adj_val, sup2, b2, out, N);
}

// Round 3
// 468.647 us; speedup vs baseline: 1.3309x; 1.3309x over previous
//
#include <hip/hip_runtime.h>
#include <hip/hip_bf16.h>
#include <math.h>

// ---------------------------------------------------------------------------
// GCN forward: out = log_softmax( A@( relu(A@(x@W1)+b1) @ W2 ) + b2 )
// Round 2: fix k_gemm2 B-staging (was copying only half of each W2t row ->
// uninitialized LDS -> NaN). bf16 intermediates + MFMA GEMMs otherwise as R1.
// ---------------------------------------------------------------------------

#define GCN_NFEAT 256
#define GCN_NHID  128
#define GCN_NCLASS 40

typedef __bf16 bf16_t;
typedef bf16_t bf16x8 __attribute__((ext_vector_type(8)));
typedef float  f32x4  __attribute__((ext_vector_type(4)));

static __device__ __forceinline__ unsigned short f2b(float f) {
    bf16_t b = (bf16_t)f;
    return *(unsigned short*)&b;
}

// ---- row_ptr[r] = lower_bound(adj_row, r), r in [0, N] ---------------------
__global__ __launch_bounds__(256) void k_row_ptr(
    const int* __restrict__ row, int* __restrict__ row_ptr, int n_rows, int n_edges)
{
    int r = blockIdx.x * blockDim.x + threadIdx.x;
    if (r > n_rows) return;
    int lo = 0, hi = n_edges;
    while (lo < hi) {
        int mid = (lo + hi) >> 1;
        if (row[mid] < r) lo = mid + 1; else hi = mid;
    }
    row_ptr[r] = lo;
}

// ---- prep: W1t_bf16[128][256] = bf16(W1[k][c]) transposed ------------------
__global__ __launch_bounds__(256) void k_prep_w1t(
    const float* __restrict__ w1, bf16_t* __restrict__ w1t)
{
    int idx = blockIdx.x * 256 + threadIdx.x;           // 128*256 total
    int c = idx & 127;                                   // coalesced read of w1 row
    int k = idx >> 7;
    w1t[(size_t)c * GCN_NFEAT + k] = (bf16_t)w1[(size_t)k * GCN_NHID + c];
}

// ---- prep: W2t_bf16[48][128], cols 40..47 zero -----------------------------
__global__ __launch_bounds__(256) void k_prep_w2t(
    const float* __restrict__ w2, bf16_t* __restrict__ w2t)
{
    int idx = blockIdx.x * 256 + threadIdx.x;           // 48*128 = 6144 total
    if (idx >= 48 * GCN_NHID) return;
    int c = idx / GCN_NHID;
    int k = idx - c * GCN_NHID;
    float v = (c < GCN_NCLASS) ? w2[(size_t)k * GCN_NCLASS + c] : 0.f;
    w2t[idx] = (bf16_t)v;
}

// ---- GEMM1 (MFMA): sup1_bf16[N,128] = bf16( x[N,256] @ W1 ) ----------------
// 128x128 tile / block (4 waves, each 64x64 = 4x4 frags of 16x16x32).
__global__ __launch_bounds__(256) void k_gemm1(
    const float* __restrict__ x, const bf16_t* __restrict__ w1t,
    bf16_t* __restrict__ out, int nrows)
{
    __shared__ __align__(16) bf16_t As[128][72];   // [row][k], pad->stride 144B
    __shared__ __align__(16) bf16_t Bs[128][72];   // [col][k]

    const int tid  = threadIdx.x;
    const int wave = tid >> 6, lane = tid & 63;
    const int wm = wave >> 1, wn = wave & 1;
    const int lm = lane & 15, quad = lane >> 4;
    const int r0 = blockIdx.x * 128;

    f32x4 acc[4][4] = {};

    for (int k0 = 0; k0 < GCN_NFEAT; k0 += 64) {
        // stage A: thread -> (row=tid/2, 32 k's), fp32->bf16
        {
            const int row = tid >> 1, half = tid & 1;
            const int gr = r0 + row;
            union { bf16_t b[32]; uint4 q[4]; } t;
            if (gr < nrows) {
                const float* p = x + (size_t)gr * GCN_NFEAT + k0 + half * 32;
#pragma unroll
                for (int i = 0; i < 8; i++) {
                    float4 v = ((const float4*)p)[i];
                    t.b[i*4+0] = (bf16_t)v.x; t.b[i*4+1] = (bf16_t)v.y;
                    t.b[i*4+2] = (bf16_t)v.z; t.b[i*4+3] = (bf16_t)v.w;
                }
            } else {
#pragma unroll
                for (int i = 0; i < 4; i++) t.q[i] = make_uint4(0,0,0,0);
            }
            uint4* dst = (uint4*)&As[row][half * 32];
#pragma unroll
            for (int i = 0; i < 4; i++) dst[i] = t.q[i];
        }
        // stage B: thread -> (col=tid/2, 32 k's) from w1t (already bf16, [col][k])
        {
            const int col = tid >> 1, half = tid & 1;
            const uint4* src = (const uint4*)(w1t + (size_t)col * GCN_NFEAT + k0 + half * 32);
            uint4* dst = (uint4*)&Bs[col][half * 32];
#pragma unroll
            for (int i = 0; i < 4; i++) dst[i] = src[i];
        }
        __syncthreads();

#pragma unroll
        for (int ks = 0; ks < 2; ks++) {
            bf16x8 af[4], bfr[4];
#pragma unroll
            for (int i = 0; i < 4; i++)
                af[i] = *(const bf16x8*)&As[wm*64 + i*16 + lm][ks*32 + quad*8];
#pragma unroll
            for (int j = 0; j < 4; j++)
                bfr[j] = *(const bf16x8*)&Bs[wn*64 + j*16 + lm][ks*32 + quad*8];
#pragma unroll
            for (int i = 0; i < 4; i++)
#pragma unroll
                for (int j = 0; j < 4; j++)
                    acc[i][j] = __builtin_amdgcn_mfma_f32_16x16x32_bf16(
                        af[i], bfr[j], acc[i][j], 0, 0, 0);
        }
        __syncthreads();
    }

    // store: D mapping col=lane&15, row=quad*4+reg
#pragma unroll
    for (int i = 0; i < 4; i++) {
#pragma unroll
        for (int reg = 0; reg < 4; reg++) {
            const int gr = r0 + wm*64 + i*16 + quad*4 + reg;
            if (gr < nrows) {
#pragma unroll
                for (int j = 0; j < 4; j++) {
                    const int gc = wn*64 + j*16 + lm;
                    out[(size_t)gr * GCN_NHID + gc] = (bf16_t)acc[i][j][reg];
                }
            }
        }
    }
}

// ---- spmm1: h_bf16[r,:] = relu( sum_e val[e]*sup1[col[e],:] + b1 ) ---------
// one wave per row; lane owns 2 of 128 cols as packed bf16x2 (uint).
__global__ __launch_bounds__(256) void k_spmm1(
    const int* __restrict__ row_ptr, const int* __restrict__ col,
    const float* __restrict__ val, const unsigned int* __restrict__ sup,
    const float* __restrict__ b1, unsigned int* __restrict__ h, int nrows)
{
    const int wid  = (blockIdx.x * blockDim.x + threadIdx.x) >> 6;
    const int lane = threadIdx.x & 63;
    if (wid >= nrows) return;
    const int e0 = row_ptr[wid];
    const int e1 = row_ptr[wid + 1];

    float ax = 0.f, ay = 0.f;
    int e = e0;
    for (; e + 3 < e1; e += 4) {
        const int c0 = col[e], c1 = col[e+1], c2 = col[e+2], c3 = col[e+3];
        const float v0 = val[e], v1 = val[e+1], v2 = val[e+2], v3 = val[e+3];
        const unsigned int u0 = sup[(size_t)c0 * 64 + lane];
        const unsigned int u1 = sup[(size_t)c1 * 64 + lane];
        const unsigned int u2 = sup[(size_t)c2 * 64 + lane];
        const unsigned int u3 = sup[(size_t)c3 * 64 + lane];
        ax = fmaf(v0, __uint_as_float(u0 << 16), ax);
        ay = fmaf(v0, __uint_as_float(u0 & 0xffff0000u), ay);
        ax = fmaf(v1, __uint_as_float(u1 << 16), ax);
        ay = fmaf(v1, __uint_as_float(u1 & 0xffff0000u), ay);
        ax = fmaf(v2, __uint_as_float(u2 << 16), ax);
        ay = fmaf(v2, __uint_as_float(u2 & 0xffff0000u), ay);
        ax = fmaf(v3, __uint_as_float(u3 << 16), ax);
        ay = fmaf(v3, __uint_as_float(u3 & 0xffff0000u), ay);
    }
    for (; e < e1; e++) {
        const unsigned int u = sup[(size_t)col[e] * 64 + lane];
        const float v = val[e];
        ax = fmaf(v, __uint_as_float(u << 16), ax);
        ay = fmaf(v, __uint_as_float(u & 0xffff0000u), ay);
    }

    const float2 bb = *(const float2*)(b1 + lane * 2);
    const float ox = fmaxf(ax + bb.x, 0.f);
    const float oy = fmaxf(ay + bb.y, 0.f);
    h[(size_t)wid * 64 + lane] = (unsigned int)f2b(ox) | ((unsigned int)f2b(oy) << 16);
}

// ---- GEMM2 (MFMA): sup2_bf16[N,40] = bf16( h[N,128] @ W2 ) -----------------
// 128 rows/block, full K=128 staged, 3 col tiles (48 cols, 40 valid).
__global__ __launch_bounds__(256) void k_gemm2(
    const bf16_t* __restrict__ h, const bf16_t* __restrict__ w2t,
    bf16_t* __restrict__ out, int nrows)
{
    __shared__ __align__(16) bf16_t As[128][136];  // [row][k], stride 272B
    __shared__ __align__(16) bf16_t Bs[48][136];   // [col][k]

    const int tid  = threadIdx.x;
    const int wave = tid >> 6, lane = tid & 63;
    const int lm = lane & 15, quad = lane >> 4;
    const int r0 = blockIdx.x * 128;

    // stage A: thread -> (row=tid/2, 64 k's) from h (bf16)
    {
        const int row = tid >> 1, half = tid & 1;
        const int gr = r0 + row;
        uint4* dst = (uint4*)&As[row][half * 64];
        if (gr < nrows) {
            const uint4* src = (const uint4*)(h + (size_t)gr * GCN_NHID + half * 64);
#pragma unroll
            for (int i = 0; i < 8; i++) dst[i] = src[i];
        } else {
#pragma unroll
            for (int i = 0; i < 8; i++) dst[i] = make_uint4(0,0,0,0);
        }
    }
    // stage B: whole W2t (48 rows x 128 bf16 = 16 uint4 per row) -- FIXED:
    // was uint2 x 16 (half a row); now uint4 x 16 covers the full 256 B row.
    for (int idx = tid; idx < 48 * 16; idx += 256) {
        const int c = idx >> 4, seg = idx & 15;
        ((uint4*)&Bs[c][0])[seg] = ((const uint4*)(w2t + (size_t)c * GCN_NHID))[seg];
    }
    __syncthreads();

    f32x4 acc[2][3] = {};
#pragma unroll
    for (int ks = 0; ks < 4; ks++) {
        bf16x8 af[2], bfr[3];
#pragma unroll
        for (int i = 0; i < 2; i++)
            af[i] = *(const bf16x8*)&As[wave*32 + i*16 + lm][ks*32 + quad*8];
#pragma unroll
        for (int j = 0; j < 3; j++)
            bfr[j] = *(const bf16x8*)&Bs[j*16 + lm][ks*32 + quad*8];
#pragma unroll
        for (int i = 0; i < 2; i++)
#pragma unroll
            for (int j = 0; j < 3; j++)
                acc[i][j] = __builtin_amdgcn_mfma_f32_16x16x32_bf16(
                    af[i], bfr[j], acc[i][j], 0, 0, 0);
    }

#pragma unroll
    for (int i = 0; i < 2; i++) {
#pragma unroll
        for (int reg = 0; reg < 4; reg++) {
            const int gr = r0 + wave*32 + i*16 + quad*4 + reg;
            if (gr < nrows) {
#pragma unroll
                for (int j = 0; j < 3; j++) {
                    const int gc = j*16 + lm;
                    if (gc < GCN_NCLASS)
                        out[(size_t)gr * GCN_NCLASS + gc] = (bf16_t)acc[i][j][reg];
                }
            }
        }
    }
}

// ---- spmm2 + bias + log_softmax -> out[N,40] fp32 --------------------------
// one wave per row; lanes 0..19 gather packed bf16x2 (2 classes each).
__global__ __launch_bounds__(256) void k_spmm2_lsm(
    const int* __restrict__ row_ptr, const int* __restrict__ col,
    const float* __restrict__ val, const unsigned int* __restrict__ sup2,
    const float* __restrict__ b2, float* __restrict__ out, int nrows)
{
    const int wid  = (blockIdx.x * blockDim.x + threadIdx.x) >> 6;
    const int lane = threadIdx.x & 63;
    if (wid >= nrows) return;
    const int e0 = row_ptr[wid];
    const int e1 = row_ptr[wid + 1];
    const bool active = lane < (GCN_NCLASS / 2);   // 20 lanes, 2 classes each

    float ax = 0.f, ay = 0.f;
    int e = e0;
    for (; e + 3 < e1; e += 4) {
        const int c0 = col[e], c1 = col[e+1], c2 = col[e+2], c3 = col[e+3];
        const float v0 = val[e], v1 = val[e+1], v2 = val[e+2], v3 = val[e+3];
        if (active) {
            const unsigned int u0 = sup2[(size_t)c0 * 20 + lane];
            const unsigned int u1 = sup2[(size_t)c1 * 20 + lane];
            const unsigned int u2 = sup2[(size_t)c2 * 20 + lane];
            const unsigned int u3 = sup2[(size_t)c3 * 20 + lane];
            ax = fmaf(v0, __uint_as_float(u0 << 16), ax);
            ay = fmaf(v0, __uint_as_float(u0 & 0xffff0000u), ay);
            ax = fmaf(v1, __uint_as_float(u1 << 16), ax);
            ay = fmaf(v1, __uint_as_float(u1 & 0xffff0000u), ay);
            ax = fmaf(v2, __uint_as_float(u2 << 16), ax);
            ay = fmaf(v2, __uint_as_float(u2 & 0xffff0000u), ay);
            ax = fmaf(v3, __uint_as_float(u3 << 16), ax);
            ay = fmaf(v3, __uint_as_float(u3 & 0xffff0000u), ay);
        }
    }
    for (; e < e1; e++) {
        if (active) {
            const unsigned int u = sup2[(size_t)col[e] * 20 + lane];
            const float v = val[e];
            ax = fmaf(v, __uint_as_float(u << 16), ax);
            ay = fmaf(v, __uint_as_float(u & 0xffff0000u), ay);
        }
    }

    float l0 = -INFINITY, l1 = -INFINITY;
    if (active) {
        l0 = ax + b2[lane * 2];
        l1 = ay + b2[lane * 2 + 1];
    }

    float m = fmaxf(l0, l1);
#pragma unroll
    for (int off = 32; off >= 1; off >>= 1)
        m = fmaxf(m, __shfl_xor(m, off, 64));

    float s = active ? (__expf(l0 - m) + __expf(l1 - m)) : 0.f;
#pragma unroll
    for (int off = 32; off >= 1; off >>= 1)
        s += __shfl_xor(s, off, 64);

    if (active) {
        const float lse = m + __logf(s);
        float* p = out + (size_t)wid * GCN_NCLASS + lane * 2;
        p[0] = l0 - lse;
        p[1] = l1 - lse;
    }
}

// ---------------------------------------------------------------------------
extern "C" void kernel_launch(void* const* d_in, const int* in_sizes, int n_in,
                              void* d_out, int out_size, void* d_ws, size_t ws_size,
                              hipStream_t stream)
{
    const float* x       = (const float*)d_in[0];
    const int*   adj_row = (const int*)  d_in[1];
    const int*   adj_col = (const int*)  d_in[2];
    const float* adj_val = (const float*)d_in[3];
    // d_in[4] = i (unused)
    const float* W1 = (const float*)d_in[5];
    const float* b1 = (const float*)d_in[6];
    const float* W2 = (const float*)d_in[7];
    const float* b2 = (const float*)d_in[8];
    float* out = (float*)d_out;

    const int N = in_sizes[0] / GCN_NFEAT;   // 100000
    const int E = in_sizes[1];               // 3200000

    // workspace layout (1 KiB aligned chunks)
    char* ws = (char*)d_ws;
    size_t off = 0;
    int* row_ptr = (int*)(ws + off);
    off += (((size_t)(N + 1) * sizeof(int)) + 1023) & ~(size_t)1023;
    bf16_t* w1t = (bf16_t*)(ws + off);                 // 128*256 bf16
    off += ((size_t)GCN_NHID * GCN_NFEAT * 2 + 1023) & ~(size_t)1023;
    bf16_t* w2t = (bf16_t*)(ws + off);                 // 48*128 bf16
    off += ((size_t)48 * GCN_NHID * 2 + 1023) & ~(size_t)1023;
    bf16_t* sup1 = (bf16_t*)(ws + off);                // N*128 bf16
    off += ((size_t)N * GCN_NHID * 2 + 1023) & ~(size_t)1023;
    bf16_t* h = (bf16_t*)(ws + off);                   // N*128 bf16
    bf16_t* sup2 = sup1;                               // reuse sup1 (N*40 bf16)

    k_row_ptr<<<(N + 1 + 255) / 256, 256, 0, stream>>>(adj_row, row_ptr, N, E);
    k_prep_w1t<<<GCN_NHID * GCN_NFEAT / 256, 256, 0, stream>>>(W1, w1t);
    k_prep_w2t<<<(48 * GCN_NHID + 255) / 256, 256, 0, stream>>>(W2, w2t);
    k_gemm1<<<(N + 127) / 128, 256, 0, stream>>>(x, w1t, sup1, N);
    k_spmm1<<<(N + 3) / 4, 256, 0, stream>>>(row_ptr, adj_col, adj_val,
                                             (const unsigned int*)sup1, b1,
                                             (unsigned int*)h, N);
    k_gemm2<<<(N + 127) / 128, 256, 0, stream>>>(h, w2t, sup2, N);
    k_spmm2_lsm<<<(N + 3) / 4, 256, 0, stream>>>(row_ptr, adj_col, adj_val,
                                                 (const unsigned int*)sup2, b2, out, N);
}

// Round 4
// 417.345 us; speedup vs baseline: 1.4946x; 1.1229x over previous
//
#include <hip/hip_runtime.h>
#include <hip/hip_bf16.h>
#include <math.h>

// ---------------------------------------------------------------------------
// GCN forward: out = log_softmax( A@( relu(A@(x@W1)+b1) @ W2 ) + b2 )
// Round 4: spmm issue-efficiency. spmm1: 16-edge chunks, col/val loaded once
// by lanes 0-15 + __shfl broadcast (loads 3/edge -> ~1.1/edge, 16 gathers in
// flight). spmm2: 3 rows per wave (20 lanes each), 4-edge unroll.
// ---------------------------------------------------------------------------

#define GCN_NFEAT 256
#define GCN_NHID  128
#define GCN_NCLASS 40

typedef __bf16 bf16_t;
typedef bf16_t bf16x8 __attribute__((ext_vector_type(8)));
typedef float  f32x4  __attribute__((ext_vector_type(4)));

static __device__ __forceinline__ unsigned short f2b(float f) {
    bf16_t b = (bf16_t)f;
    return *(unsigned short*)&b;
}
static __device__ __forceinline__ float blo(unsigned int u) {
    return __uint_as_float(u << 16);
}
static __device__ __forceinline__ float bhi(unsigned int u) {
    return __uint_as_float(u & 0xffff0000u);
}

// ---- row_ptr[r] = lower_bound(adj_row, r), r in [0, N] ---------------------
__global__ __launch_bounds__(256) void k_row_ptr(
    const int* __restrict__ row, int* __restrict__ row_ptr, int n_rows, int n_edges)
{
    int r = blockIdx.x * blockDim.x + threadIdx.x;
    if (r > n_rows) return;
    int lo = 0, hi = n_edges;
    while (lo < hi) {
        int mid = (lo + hi) >> 1;
        if (row[mid] < r) lo = mid + 1; else hi = mid;
    }
    row_ptr[r] = lo;
}

// ---- prep: W1t_bf16[128][256] = bf16(W1[k][c]) transposed ------------------
__global__ __launch_bounds__(256) void k_prep_w1t(
    const float* __restrict__ w1, bf16_t* __restrict__ w1t)
{
    int idx = blockIdx.x * 256 + threadIdx.x;           // 128*256 total
    int c = idx & 127;
    int k = idx >> 7;
    w1t[(size_t)c * GCN_NFEAT + k] = (bf16_t)w1[(size_t)k * GCN_NHID + c];
}

// ---- prep: W2t_bf16[48][128], cols 40..47 zero -----------------------------
__global__ __launch_bounds__(256) void k_prep_w2t(
    const float* __restrict__ w2, bf16_t* __restrict__ w2t)
{
    int idx = blockIdx.x * 256 + threadIdx.x;           // 48*128 = 6144 total
    if (idx >= 48 * GCN_NHID) return;
    int c = idx / GCN_NHID;
    int k = idx - c * GCN_NHID;
    float v = (c < GCN_NCLASS) ? w2[(size_t)k * GCN_NCLASS + c] : 0.f;
    w2t[idx] = (bf16_t)v;
}

// ---- GEMM1 (MFMA): sup1_bf16[N,128] = bf16( x[N,256] @ W1 ) ----------------
__global__ __launch_bounds__(256) void k_gemm1(
    const float* __restrict__ x, const bf16_t* __restrict__ w1t,
    bf16_t* __restrict__ out, int nrows)
{
    __shared__ __align__(16) bf16_t As[128][72];   // [row][k]
    __shared__ __align__(16) bf16_t Bs[128][72];   // [col][k]

    const int tid  = threadIdx.x;
    const int wave = tid >> 6, lane = tid & 63;
    const int wm = wave >> 1, wn = wave & 1;
    const int lm = lane & 15, quad = lane >> 4;
    const int r0 = blockIdx.x * 128;

    f32x4 acc[4][4] = {};

    for (int k0 = 0; k0 < GCN_NFEAT; k0 += 64) {
        {
            const int row = tid >> 1, half = tid & 1;
            const int gr = r0 + row;
            union { bf16_t b[32]; uint4 q[4]; } t;
            if (gr < nrows) {
                const float* p = x + (size_t)gr * GCN_NFEAT + k0 + half * 32;
#pragma unroll
                for (int i = 0; i < 8; i++) {
                    float4 v = ((const float4*)p)[i];
                    t.b[i*4+0] = (bf16_t)v.x; t.b[i*4+1] = (bf16_t)v.y;
                    t.b[i*4+2] = (bf16_t)v.z; t.b[i*4+3] = (bf16_t)v.w;
                }
            } else {
#pragma unroll
                for (int i = 0; i < 4; i++) t.q[i] = make_uint4(0,0,0,0);
            }
            uint4* dst = (uint4*)&As[row][half * 32];
#pragma unroll
            for (int i = 0; i < 4; i++) dst[i] = t.q[i];
        }
        {
            const int colc = tid >> 1, half = tid & 1;
            const uint4* src = (const uint4*)(w1t + (size_t)colc * GCN_NFEAT + k0 + half * 32);
            uint4* dst = (uint4*)&Bs[colc][half * 32];
#pragma unroll
            for (int i = 0; i < 4; i++) dst[i] = src[i];
        }
        __syncthreads();

#pragma unroll
        for (int ks = 0; ks < 2; ks++) {
            bf16x8 af[4], bfr[4];
#pragma unroll
            for (int i = 0; i < 4; i++)
                af[i] = *(const bf16x8*)&As[wm*64 + i*16 + lm][ks*32 + quad*8];
#pragma unroll
            for (int j = 0; j < 4; j++)
                bfr[j] = *(const bf16x8*)&Bs[wn*64 + j*16 + lm][ks*32 + quad*8];
#pragma unroll
            for (int i = 0; i < 4; i++)
#pragma unroll
                for (int j = 0; j < 4; j++)
                    acc[i][j] = __builtin_amdgcn_mfma_f32_16x16x32_bf16(
                        af[i], bfr[j], acc[i][j], 0, 0, 0);
        }
        __syncthreads();
    }

#pragma unroll
    for (int i = 0; i < 4; i++) {
#pragma unroll
        for (int reg = 0; reg < 4; reg++) {
            const int gr = r0 + wm*64 + i*16 + quad*4 + reg;
            if (gr < nrows) {
#pragma unroll
                for (int j = 0; j < 4; j++) {
                    const int gc = wn*64 + j*16 + lm;
                    out[(size_t)gr * GCN_NHID + gc] = (bf16_t)acc[i][j][reg];
                }
            }
        }
    }
}

// ---- spmm1: h_bf16[r,:] = relu( sum_e val[e]*sup1[col[e],:] + b1 ) ---------
// wave per row; 16-edge chunks: lanes 0-15 load col/val once, shfl-broadcast;
// 16 independent gathers in flight per chunk; 32-bit gather indices.
__global__ __launch_bounds__(256) void k_spmm1(
    const int* __restrict__ row_ptr, const int* __restrict__ col,
    const float* __restrict__ val, const unsigned int* __restrict__ sup,
    const float* __restrict__ b1, unsigned int* __restrict__ h, int nrows)
{
    const int wid  = (blockIdx.x * blockDim.x + threadIdx.x) >> 6;
    const int lane = threadIdx.x & 63;
    if (wid >= nrows) return;
    const int e0 = row_ptr[wid];
    const int e1 = row_ptr[wid + 1];
    const int sub = lane & 15;

    float ax = 0.f, ay = 0.f;
    int e = e0;
    for (; e + 16 <= e1; e += 16) {
        const int   cv = col[e + sub];
        const float vv = val[e + sub];
#pragma unroll
        for (int j = 0; j < 16; j++) {
            const int   cj = __shfl(cv, j, 64);
            const float vj = __shfl(vv, j, 64);
            const unsigned int u = sup[(unsigned)(cj << 6) + lane];
            ax = fmaf(vj, blo(u), ax);
            ay = fmaf(vj, bhi(u), ay);
        }
    }
    for (; e < e1; e++) {
        const int c = col[e];
        const float v = val[e];
        const unsigned int u = sup[(unsigned)(c << 6) + lane];
        ax = fmaf(v, blo(u), ax);
        ay = fmaf(v, bhi(u), ay);
    }

    const float2 bb = *(const float2*)(b1 + lane * 2);
    const float ox = fmaxf(ax + bb.x, 0.f);
    const float oy = fmaxf(ay + bb.y, 0.f);
    h[(unsigned)(wid << 6) + lane] = (unsigned int)f2b(ox) | ((unsigned int)f2b(oy) << 16);
}

// ---- GEMM2 (MFMA): sup2_bf16[N,40] = bf16( h[N,128] @ W2 ) -----------------
__global__ __launch_bounds__(256) void k_gemm2(
    const bf16_t* __restrict__ h, const bf16_t* __restrict__ w2t,
    bf16_t* __restrict__ out, int nrows)
{
    __shared__ __align__(16) bf16_t As[128][136];  // [row][k]
    __shared__ __align__(16) bf16_t Bs[48][136];   // [col][k]

    const int tid  = threadIdx.x;
    const int wave = tid >> 6, lane = tid & 63;
    const int lm = lane & 15, quad = lane >> 4;
    const int r0 = blockIdx.x * 128;

    {
        const int row = tid >> 1, half = tid & 1;
        const int gr = r0 + row;
        uint4* dst = (uint4*)&As[row][half * 64];
        if (gr < nrows) {
            const uint4* src = (const uint4*)(h + (size_t)gr * GCN_NHID + half * 64);
#pragma unroll
            for (int i = 0; i < 8; i++) dst[i] = src[i];
        } else {
#pragma unroll
            for (int i = 0; i < 8; i++) dst[i] = make_uint4(0,0,0,0);
        }
    }
    // stage B: 48 rows x 16 uint4 (full 256 B row)
    for (int idx = tid; idx < 48 * 16; idx += 256) {
        const int c = idx >> 4, seg = idx & 15;
        ((uint4*)&Bs[c][0])[seg] = ((const uint4*)(w2t + (size_t)c * GCN_NHID))[seg];
    }
    __syncthreads();

    f32x4 acc[2][3] = {};
#pragma unroll
    for (int ks = 0; ks < 4; ks++) {
        bf16x8 af[2], bfr[3];
#pragma unroll
        for (int i = 0; i < 2; i++)
            af[i] = *(const bf16x8*)&As[wave*32 + i*16 + lm][ks*32 + quad*8];
#pragma unroll
        for (int j = 0; j < 3; j++)
            bfr[j] = *(const bf16x8*)&Bs[j*16 + lm][ks*32 + quad*8];
#pragma unroll
        for (int i = 0; i < 2; i++)
#pragma unroll
            for (int j = 0; j < 3; j++)
                acc[i][j] = __builtin_amdgcn_mfma_f32_16x16x32_bf16(
                    af[i], bfr[j], acc[i][j], 0, 0, 0);
    }

#pragma unroll
    for (int i = 0; i < 2; i++) {
#pragma unroll
        for (int reg = 0; reg < 4; reg++) {
            const int gr = r0 + wave*32 + i*16 + quad*4 + reg;
            if (gr < nrows) {
#pragma unroll
                for (int j = 0; j < 3; j++) {
                    const int gc = j*16 + lm;
                    if (gc < GCN_NCLASS)
                        out[(size_t)gr * GCN_NCLASS + gc] = (bf16_t)acc[i][j][reg];
                }
            }
        }
    }
}

// ---- spmm2 + bias + log_softmax -> out[N,40] fp32 --------------------------
// 3 rows per wave: group g = lane/20 handles row wid*3+g, li = lane%20 owns
// classes {2li, 2li+1} packed in one uint. One load instr serves all 3 groups.
__global__ __launch_bounds__(256) void k_spmm2_lsm(
    const int* __restrict__ row_ptr, const int* __restrict__ col,
    const float* __restrict__ val, const unsigned int* __restrict__ sup2,
    const float* __restrict__ b2, float* __restrict__ out, int nrows)
{
    const int wid  = (blockIdx.x * blockDim.x + threadIdx.x) >> 6;
    const int lane = threadIdx.x & 63;
    const int g    = lane / 20;            // 0..2 valid, 3 = idle lanes 60-63
    const int li   = lane - g * 20;
    const int r    = wid * 3 + g;
    const bool active = (g < 3) && (r < nrows);

    int e0 = 0, e1 = 0;
    if (active) { e0 = row_ptr[r]; e1 = row_ptr[r + 1]; }

    float ax = 0.f, ay = 0.f;
    int e = e0;
    for (; e + 3 < e1; e += 4) {
        const int c0 = col[e],   c1 = col[e+1], c2 = col[e+2], c3 = col[e+3];
        const float v0 = val[e], v1 = val[e+1], v2 = val[e+2], v3 = val[e+3];
        const unsigned int u0 = sup2[(unsigned)(c0 * 20) + li];
        const unsigned int u1 = sup2[(unsigned)(c1 * 20) + li];
        const unsigned int u2 = sup2[(unsigned)(c2 * 20) + li];
        const unsigned int u3 = sup2[(unsigned)(c3 * 20) + li];
        ax = fmaf(v0, blo(u0), ax); ay = fmaf(v0, bhi(u0), ay);
        ax = fmaf(v1, blo(u1), ax); ay = fmaf(v1, bhi(u1), ay);
        ax = fmaf(v2, blo(u2), ax); ay = fmaf(v2, bhi(u2), ay);
        ax = fmaf(v3, blo(u3), ax); ay = fmaf(v3, bhi(u3), ay);
    }
    for (; e < e1; e++) {
        const unsigned int u = sup2[(unsigned)(col[e] * 20) + li];
        const float v = val[e];
        ax = fmaf(v, blo(u), ax); ay = fmaf(v, bhi(u), ay);
    }

    float l0 = -INFINITY, l1 = -INFINITY;
    if (active) {
        l0 = ax + b2[li * 2];
        l1 = ay + b2[li * 2 + 1];
    }

    // group-local (20-lane) shuffle reductions
    float m = fmaxf(l0, l1);
#pragma unroll
    for (int off = 16; off >= 1; off >>= 1) {
        const float t = __shfl_down(m, off, 64);
        if (li + off < 20) m = fmaxf(m, t);
    }
    m = __shfl(m, g * 20, 64);   // broadcast group max

    float s = active ? (__expf(l0 - m) + __expf(l1 - m)) : 0.f;
#pragma unroll
    for (int off = 16; off >= 1; off >>= 1) {
        const float t = __shfl_down(s, off, 64);
        if (li + off < 20) s += t;
    }
    s = __shfl(s, g * 20, 64);

    if (active) {
        const float lse = m + __logf(s);
        float* p = out + (size_t)r * GCN_NCLASS + li * 2;
        p[0] = l0 - lse;
        p[1] = l1 - lse;
    }
}

// ---------------------------------------------------------------------------
extern "C" void kernel_launch(void* const* d_in, const int* in_sizes, int n_in,
                              void* d_out, int out_size, void* d_ws, size_t ws_size,
                              hipStream_t stream)
{
    const float* x       = (const float*)d_in[0];
    const int*   adj_row = (const int*)  d_in[1];
    const int*   adj_col = (const int*)  d_in[2];
    const float* adj_val = (const float*)d_in[3];
    // d_in[4] = i (unused)
    const float* W1 = (const float*)d_in[5];
    const float* b1 = (const float*)d_in[6];
    const float* W2 = (const float*)d_in[7];
    const float* b2 = (const float*)d_in[8];
    float* out = (float*)d_out;

    const int N = in_sizes[0] / GCN_NFEAT;   // 100000
    const int E = in_sizes[1];               // 3200000

    // workspace layout (1 KiB aligned chunks)
    char* ws = (char*)d_ws;
    size_t off = 0;
    int* row_ptr = (int*)(ws + off);
    off += (((size_t)(N + 1) * sizeof(int)) + 1023) & ~(size_t)1023;
    bf16_t* w1t = (bf16_t*)(ws + off);                 // 128*256 bf16
    off += ((size_t)GCN_NHID * GCN_NFEAT * 2 + 1023) & ~(size_t)1023;
    bf16_t* w2t = (bf16_t*)(ws + off);                 // 48*128 bf16
    off += ((size_t)48 * GCN_NHID * 2 + 1023) & ~(size_t)1023;
    bf16_t* sup1 = (bf16_t*)(ws + off);                // N*128 bf16
    off += ((size_t)N * GCN_NHID * 2 + 1023) & ~(size_t)1023;
    bf16_t* h = (bf16_t*)(ws + off);                   // N*128 bf16
    bf16_t* sup2 = sup1;                               // reuse sup1 (N*40 bf16)

    k_row_ptr<<<(N + 1 + 255) / 256, 256, 0, stream>>>(adj_row, row_ptr, N, E);
    k_prep_w1t<<<GCN_NHID * GCN_NFEAT / 256, 256, 0, stream>>>(W1, w1t);
    k_prep_w2t<<<(48 * GCN_NHID + 255) / 256, 256, 0, stream>>>(W2, w2t);
    k_gemm1<<<(N + 127) / 128, 256, 0, stream>>>(x, w1t, sup1, N);
    k_spmm1<<<(N + 3) / 4, 256, 0, stream>>>(row_ptr, adj_col, adj_val,
                                             (const unsigned int*)sup1, b1,
                                             (unsigned int*)h, N);
    k_gemm2<<<(N + 127) / 128, 256, 0, stream>>>(h, w2t, sup2, N);
    const int nw2 = (N + 2) / 3;                       // waves for spmm2
    k_spmm2_lsm<<<(nw2 + 3) / 4, 256, 0, stream>>>(row_ptr, adj_col, adj_val,
                                                   (const unsigned int*)sup2, b2, out, N);
}